// Round 13
// baseline (143.064 us; speedup 1.0000x reference)
//
#include <hip/hip_runtime.h>
#include <hip/hip_bf16.h>
#include <stdint.h>

// ChebyKAN: y[b,o] = sum_{i,d} T_d(tanh(x[b,i])) * c[i,o,d]
//   == GEMM [16384 x 4096] x [4096 x 512]  (d=1..8; d=0 via column-sum)
//
// R12: in-register A + half-phase pipelining, register-budgeted.
// - LDS floor analysis (m134: ds b128 ~12cy): R6's A round trip made LDS
//   the binding pipe (~51us > 33us MFMA floor). A now never touches LDS.
// - Each 16-MFMA half-cluster (afA) interleaves with pure-VALU generation
//   of the next half's fragments (afB): Tn=fma(t2,Tp,-Tpp), pack. No
//   serial VALU->MFMA wall; INIT(tanh) folded into qq==3 slack.
// - Registers ~236 (state 96, acc 64, af 32, frags 16, x<=16): no spill
//   (R11 spilled at ~280 -> WRITE_SIZE 97MB).
// - Sync: R9's proven skeleton (vmcnt(4) BEFORE barrier-1; 2 buf; barrier-2
//   after MFMA; never vmcnt(0) in loop). x loads pinned ahead of B issues.

#define BM 128
#define BN 128
#define IN_DIM 512
#define OUT_DIM 512

typedef __attribute__((ext_vector_type(8))) short short8;
typedef __attribute__((ext_vector_type(4))) float f32x4;

__device__ __forceinline__ unsigned short f2bf(float f) {
  __hip_bfloat16 h = __float2bfloat16(f);
  return __builtin_bit_cast(unsigned short, h);
}

__device__ __forceinline__ float fast_tanh(float v) {
  float e = __expf(v + v);
  return 1.0f - 2.0f * __builtin_amdgcn_rcpf(e + 1.0f);
}

__device__ __forceinline__ void gload_lds16(const void* g, void* l) {
  __builtin_amdgcn_global_load_lds(
      (const __attribute__((address_space(1))) unsigned int*)(uintptr_t)g,
      (__attribute__((address_space(3))) unsigned int*)(uintptr_t)l,
      16, 0, 0);
}

// ---------------------------------------------------------------------------
// Kernel 1: coeffs[i][o][d] (f32) -> ws: bf16 B^T chunks, pre-swizzled.
// Chunk (nb, c) with c = itile*4 + p is a 16KB image of LDS tile
// [nl 0..127][128 B]: elem (il, dl) at byte nl*128 + ((dl*64+il*2)^((nl&7)<<4)),
// holding coeff d = 1 + 2p + dl.   (unchanged from R6..R9)
// ---------------------------------------------------------------------------
__global__ __launch_bounds__(256) void cheby_reorder_b(
    const float* __restrict__ coeffs, unsigned char* __restrict__ bws) {
  const int g = blockIdx.x * 256 + threadIdx.x;  // 512*512 threads
  const int i = g & 511;
  const int o = g >> 9;
  const int nb = o >> 7, nl = o & 127;
  const int itile = i >> 5, il = i & 31;
  const float* cp = coeffs + (size_t)i * 4608 + (size_t)o * 9;
  const int swz = (nl & 7) << 4;
#pragma unroll
  for (int p = 0; p < 4; ++p) {
    const size_t base =
        ((size_t)(nb * 64 + itile * 4 + p) << 14) + (size_t)nl * 128;
    *(unsigned short*)(bws + base + ((il * 2) ^ swz)) = f2bf(cp[1 + 2 * p]);
    *(unsigned short*)(bws + base + ((64 + il * 2) ^ swz)) =
        f2bf(cp[2 + 2 * p]);
  }
}

// ---------------------------------------------------------------------------
// Kernel 2: colsum[o] = sum_i coeffs[i][o][0]   (T_0 == 1 contribution)
// ---------------------------------------------------------------------------
__global__ __launch_bounds__(64) void cheby_colsum(
    const float* __restrict__ coeffs, float* __restrict__ cs) {
  const int o = blockIdx.x;
  const int l = threadIdx.x;
  float s = 0.0f;
#pragma unroll
  for (int j = 0; j < 8; ++j)
    s += coeffs[(size_t)(l + j * 64) * 4608 + (size_t)o * 9];
#pragma unroll
  for (int off = 32; off > 0; off >>= 1) s += __shfl_down(s, off, 64);
  if (l == 0) cs[o] = s;
}

// ---------------------------------------------------------------------------
// Kernel 3: fused basis-gen + bf16 MFMA GEMM.
// 128x128 tile, 4 waves 64x64, 16x16x32 mfma, in-reg A, half-phase pipeline.
// ---------------------------------------------------------------------------
#define ISSUE_B(SNEXT, PBUF)                                              \
  {                                                                       \
    const unsigned char* gsrc = bchunk0 + ((size_t)(SNEXT) << 14) + goff; \
    unsigned char* ldst = &Bs[PBUF][0] + wid * 4096;                      \
    gload_lds16(gsrc, ldst);                                              \
    gload_lds16(gsrc + 1024, ldst + 1024);                                \
    gload_lds16(gsrc + 2048, ldst + 2048);                                \
    gload_lds16(gsrc + 3072, ldst + 3072);                                \
  }

// load x rows R0, R0+1 of this lane's 4 owned rows (8 f32 each)
#define LOAD_X2(IT, R0)                                                   \
  {                                                                       \
    _Pragma("unroll") for (int fm = (R0); fm < (R0) + 2; ++fm) {          \
      const float* xp = xrow[fm] + (IT) * 32;                             \
      xa[fm] = reinterpret_cast<const float4*>(xp)[0];                    \
      xb[fm] = reinterpret_cast<const float4*>(xp)[1];                    \
    }                                                                     \
    __builtin_amdgcn_sched_barrier(0);                                    \
  }

// advance chain one degree for all 32 states; pack into AF
#define GEN(AF)                                                           \
  {                                                                       \
    _Pragma("unroll") for (int fm = 0; fm < 4; ++fm)                      \
        _Pragma("unroll") for (int j = 0; j < 8; ++j) {                   \
      const float Tn = __builtin_fmaf(t2[fm][j], Tp[fm][j], -Tpp[fm][j]); \
      Tpp[fm][j] = Tp[fm][j];                                             \
      Tp[fm][j] = Tn;                                                     \
      AF[fm][j] = (short)f2bf(Tn);                                        \
    }                                                                     \
  }

// (re)initialize chain from x for rows R0, R0+1: Tp=T1=tanh, Tpp=T0=1
#define INIT2(AF, R0)                                                     \
  {                                                                       \
    _Pragma("unroll") for (int fm = (R0); fm < (R0) + 2; ++fm)            \
        _Pragma("unroll") for (int j = 0; j < 8; ++j) {                   \
      const float xv = (j < 4) ? ((const float*)&xa[fm])[j & 3]           \
                               : ((const float*)&xb[fm])[j & 3];          \
      const float th = fast_tanh(xv);                                     \
      t2[fm][j] = th + th;                                                \
      Tp[fm][j] = th;                                                     \
      Tpp[fm][j] = 1.0f;                                                  \
      AF[fm][j] = (short)f2bf(th);                                        \
    }                                                                     \
  }

#define READ_B(KS, BF)                                                    \
  {                                                                       \
    _Pragma("unroll") for (int fn = 0; fn < 4; ++fn) {                    \
      const int row = wn + fn * 16 + l15;                                 \
      const int rsw = (row & 7) << 4;                                     \
      BF[fn] = *(const short8*)(Bcur + row * 128 +                        \
                                (((KS) * 64 + lhi * 16) ^ rsw));          \
    }                                                                     \
  }

#define MFMA16(AF, BF)                                                    \
  {                                                                       \
    __builtin_amdgcn_s_setprio(1);                                        \
    _Pragma("unroll") for (int fn = 0; fn < 4; ++fn)                      \
        _Pragma("unroll") for (int fm = 0; fm < 4; ++fm)                  \
            acc[fm][fn] = __builtin_amdgcn_mfma_f32_16x16x32_bf16(        \
                AF[fm], BF[fn], acc[fm][fn], 0, 0, 0);                    \
    __builtin_amdgcn_s_setprio(0);                                        \
  }

// one K-tile (64 k = 2 degrees). QQ static 0..3; buffer parity = QQ&1.
#define TILE(IT, QQ)                                                      \
  {                                                                       \
    const int s_ = (IT) * 4 + (QQ);                                       \
    const int itn_ = ((IT) < 15) ? (IT) + 1 : 15;                         \
    if ((QQ) == 2) LOAD_X2(itn_, 0);                                      \
    if ((QQ) == 3) LOAD_X2(itn_, 2);                                      \
    ISSUE_B((s_ < 63) ? s_ + 1 : 63, ((QQ)&1) ^ 1);                       \
    asm volatile("s_waitcnt vmcnt(4)" ::: "memory");                      \
    __builtin_amdgcn_s_barrier();                                         \
    const unsigned char* Bcur = &Bs[(QQ)&1][0];                           \
    short8 bf0[4], bf1[4];                                                \
    READ_B(0, bf0);                                                       \
    MFMA16(afA, bf0);     /* consumes T_{1+2*QQ} */                       \
    GEN(afB);             /* -> T_{2+2*QQ} */                             \
    if ((QQ) == 3) INIT2(afA, 0);                                         \
    READ_B(1, bf1);                                                       \
    MFMA16(afB, bf1);     /* consumes T_{2+2*QQ} */                       \
    if ((QQ) == 3) { INIT2(afA, 2); } else { GEN(afA); } /* T_{3+2*QQ} */ \
    __builtin_amdgcn_s_barrier();                                         \
  }

__global__ __launch_bounds__(256, 2) void cheby_gemm(
    const float* __restrict__ x, const unsigned char* __restrict__ bws,
    const float* __restrict__ colsum, float* __restrict__ out) {
  const int bid = blockIdx.x;
  const int m0 = (bid >> 2) * BM;
  const int nblk = bid & 3;
  const int n0 = nblk * BN;
  const int tid = threadIdx.x;
  const int lane = tid & 63;
  const int wid = tid >> 6;          // 0..3
  const int wm = (wid >> 1) * 64;
  const int wn = (wid & 1) * 64;
  const int l15 = lane & 15;
  const int lhi = lane >> 4;

  __shared__ __align__(16) unsigned char Bs[2][BN * 128];  // 2 x 16KB

  // per-lane A ownership: rows m0+wm+fm*16+l15 (fm=0..3), i = it*32+lhi*8+j
  const float* xrow[4];
#pragma unroll
  for (int fm = 0; fm < 4; ++fm)
    xrow[fm] = x + (size_t)(m0 + wm + fm * 16 + l15) * IN_DIM + lhi * 8;

  float t2[4][8], Tp[4][8], Tpp[4][8];
  short8 afA[4], afB[4];
  float4 xa[4], xb[4];
  f32x4 acc[4][4];
#pragma unroll
  for (int a = 0; a < 4; ++a)
#pragma unroll
    for (int b = 0; b < 4; ++b) acc[a][b] = (f32x4){0.f, 0.f, 0.f, 0.f};

  const unsigned char* bchunk0 = bws + ((size_t)(nblk * 64) << 14);
  const int goff = wid * 4096 + lane * 16;

  // ---- prologue: x(it0), B(0) in flight, afA = T1
  LOAD_X2(0, 0);
  LOAD_X2(0, 2);
  ISSUE_B(0, 0);
  INIT2(afA, 0);
  INIT2(afA, 2);

  for (int it = 0; it < 16; ++it) {
    TILE(it, 0);
    TILE(it, 1);
    TILE(it, 2);
    TILE(it, 3);
  }

  // retire the trailing dummy prefetch before the epilogue stores.
  asm volatile("s_waitcnt vmcnt(0)" ::: "memory");

  // ---- epilogue: add d=0 colsum, store f32
  float csv[4];
#pragma unroll
  for (int fn = 0; fn < 4; ++fn) csv[fn] = colsum[n0 + wn + fn * 16 + l15];
  const int lhi4 = lhi * 4;
#pragma unroll
  for (int fm = 0; fm < 4; ++fm) {
    const int r0 = m0 + wm + fm * 16 + lhi4;
#pragma unroll
    for (int fn = 0; fn < 4; ++fn) {
      const int col = n0 + wn + fn * 16 + l15;
#pragma unroll
      for (int r = 0; r < 4; ++r)
        out[(size_t)(r0 + r) * OUT_DIM + col] = acc[fm][fn][r] + csv[fn];
    }
  }
}

extern "C" void kernel_launch(void* const* d_in, const int* in_sizes, int n_in,
                              void* d_out, int out_size, void* d_ws,
                              size_t ws_size, hipStream_t stream) {
  const float* x = (const float*)d_in[0];           // [16384, 512] f32
  const float* coeffs = (const float*)d_in[1];      // [512, 512, 9] f32
  float* out = (float*)d_out;                       // [16384, 512] f32
  unsigned char* bws = (unsigned char*)d_ws;        // 4MB bf16 B tiles
  float* cs = (float*)((unsigned char*)d_ws + ((size_t)4 << 20));  // +2KB

  hipLaunchKernelGGL(cheby_reorder_b, dim3(1024), dim3(256), 0, stream, coeffs,
                     bws);
  hipLaunchKernelGGL(cheby_colsum, dim3(512), dim3(64), 0, stream, coeffs, cs);
  hipLaunchKernelGGL(cheby_gemm, dim3(512), dim3(256), 0, stream, x, bws, cs,
                     out);
}

// Round 14
// 116.580 us; speedup vs baseline: 1.2272x; 1.2272x over previous
//
#include <hip/hip_runtime.h>
#include <hip/hip_bf16.h>
#include <stdint.h>

// ChebyKAN: y[b,o] = sum_{i,d} T_d(tanh(x[b,i])) * c[i,o,d]
//   == GEMM [16384 x 4096] x [4096 x 512]  (d=1..8; d=0 via column-sum)
//
// R13: in-register A, pipelined with a MINIMAL live set (R11/R12 spilled at
// ~270 regs; R9's bf-in-fn-loop shape didn't). Per step: MFMA0 consumes afC
// packed LAST step; GEN_A (in-place fma, zero temps) packs af1 under MFMA0;
// MFMA1(af1); GEN_B packs afN for next step under MFMA1. State updates are
// in-place: GEN_A: Tpp=fma(t2,Tp,-Tpp); GEN_B: Tp=fma(t2,Tpp,-Tp).
// B: pre-swizzled ws tiles -> LDS, 2 buffers, R9's race-free sync
// (per-wave counted vmcnt BEFORE barrier-1; no vmcnt(0) in loop).

#define BM 128
#define BN 128
#define IN_DIM 512
#define OUT_DIM 512

typedef __attribute__((ext_vector_type(8))) short short8;
typedef __attribute__((ext_vector_type(4))) float f32x4;

__device__ __forceinline__ unsigned short f2bf(float f) {
  __hip_bfloat16 h = __float2bfloat16(f);
  return __builtin_bit_cast(unsigned short, h);
}

__device__ __forceinline__ float fast_tanh(float v) {
  float e = __expf(v + v);
  return 1.0f - 2.0f * __builtin_amdgcn_rcpf(e + 1.0f);
}

__device__ __forceinline__ void gload_lds16(const void* g, void* l) {
  __builtin_amdgcn_global_load_lds(
      (const __attribute__((address_space(1))) unsigned int*)(uintptr_t)g,
      (__attribute__((address_space(3))) unsigned int*)(uintptr_t)l,
      16, 0, 0);
}

// ---------------------------------------------------------------------------
// Kernel 1: coeffs[i][o][d] (f32) -> ws: bf16 B^T chunks, pre-swizzled.
// Chunk (nb, c) with c = itile*4 + p is a 16KB image of LDS tile
// [nl 0..127][128 B]: elem (il, dl) at byte nl*128 + ((dl*64+il*2)^((nl&7)<<4)),
// holding coeff d = 1 + 2p + dl.   (unchanged from R6..R12)
// ---------------------------------------------------------------------------
__global__ __launch_bounds__(256) void cheby_reorder_b(
    const float* __restrict__ coeffs, unsigned char* __restrict__ bws) {
  const int g = blockIdx.x * 256 + threadIdx.x;  // 512*512 threads
  const int i = g & 511;
  const int o = g >> 9;
  const int nb = o >> 7, nl = o & 127;
  const int itile = i >> 5, il = i & 31;
  const float* cp = coeffs + (size_t)i * 4608 + (size_t)o * 9;
  const int swz = (nl & 7) << 4;
#pragma unroll
  for (int p = 0; p < 4; ++p) {
    const size_t base =
        ((size_t)(nb * 64 + itile * 4 + p) << 14) + (size_t)nl * 128;
    *(unsigned short*)(bws + base + ((il * 2) ^ swz)) = f2bf(cp[1 + 2 * p]);
    *(unsigned short*)(bws + base + ((64 + il * 2) ^ swz)) =
        f2bf(cp[2 + 2 * p]);
  }
}

// ---------------------------------------------------------------------------
// Kernel 2: colsum[o] = sum_i coeffs[i][o][0]   (T_0 == 1 contribution)
// ---------------------------------------------------------------------------
__global__ __launch_bounds__(64) void cheby_colsum(
    const float* __restrict__ coeffs, float* __restrict__ cs) {
  const int o = blockIdx.x;
  const int l = threadIdx.x;
  float s = 0.0f;
#pragma unroll
  for (int j = 0; j < 8; ++j)
    s += coeffs[(size_t)(l + j * 64) * 4608 + (size_t)o * 9];
#pragma unroll
  for (int off = 32; off > 0; off >>= 1) s += __shfl_down(s, off, 64);
  if (l == 0) cs[o] = s;
}

// ---------------------------------------------------------------------------
// Kernel 3: fused basis-gen + bf16 MFMA GEMM, in-reg A, 1.5-deep af pipeline.
// 128x128 tile, 4 waves 64x64, 16x16x32 mfma, 4x4 frags.
// ---------------------------------------------------------------------------
#define ISSUE_B(SNEXT, PBUF)                                              \
  {                                                                       \
    const unsigned char* gsrc = bchunk0 + ((size_t)(SNEXT) << 14) + goff; \
    unsigned char* ldst = &Bs[PBUF][0] + wid * 4096;                      \
    gload_lds16(gsrc, ldst);                                              \
    gload_lds16(gsrc + 1024, ldst + 1024);                                \
    gload_lds16(gsrc + 2048, ldst + 2048);                                \
    gload_lds16(gsrc + 3072, ldst + 3072);                                \
  }

// 16 MFMAs: bf read per-fn (8 live regs), AF fixed operand.
#define MFMA_SLICE(AF, OFS)                                               \
  {                                                                       \
    _Pragma("unroll") for (int fn = 0; fn < 4; ++fn) {                    \
      const short8 bf =                                                   \
          *(const short8*)(Bcur + browbase + fn * 2048 + (OFS));          \
      _Pragma("unroll") for (int fm = 0; fm < 4; ++fm)                    \
          acc[fm][fn] = __builtin_amdgcn_mfma_f32_16x16x32_bf16(          \
              AF[fm], bf, acc[fm][fn], 0, 0, 0);                          \
    }                                                                     \
  }

// GEN_A: Tpp <- fma(t2, Tp, -Tpp) (next even-degree), pack into DST.
#define GEN_A(DST)                                                        \
  {                                                                       \
    _Pragma("unroll") for (int fm = 0; fm < 4; ++fm)                      \
        _Pragma("unroll") for (int j = 0; j < 8; ++j) {                   \
      Tpp[fm][j] = __builtin_fmaf(t2[fm][j], Tp[fm][j], -Tpp[fm][j]);     \
      DST[fm][j] = (short)f2bf(Tpp[fm][j]);                               \
    }                                                                     \
  }

// GEN_B: Tp <- fma(t2, Tpp, -Tp) (next odd-degree), pack into DST.
#define GEN_B(DST)                                                        \
  {                                                                       \
    _Pragma("unroll") for (int fm = 0; fm < 4; ++fm)                      \
        _Pragma("unroll") for (int j = 0; j < 8; ++j) {                   \
      Tp[fm][j] = __builtin_fmaf(t2[fm][j], Tpp[fm][j], -Tp[fm][j]);      \
      DST[fm][j] = (short)f2bf(Tp[fm][j]);                                \
    }                                                                     \
  }

// load 2 rows' x (2 float4 each) into xv[R0..R0+1]
#define LOAD_X2(IT, R0)                                                   \
  {                                                                       \
    _Pragma("unroll") for (int fm = (R0); fm < (R0) + 2; ++fm) {          \
      const float* xp = xrow[fm] + (IT) * 32;                             \
      xv[fm][0] = reinterpret_cast<const float4*>(xp)[0];                 \
      xv[fm][1] = reinterpret_cast<const float4*>(xp)[1];                 \
    }                                                                     \
  }

// re-init chain from x for rows R0..R0+1: Tp=T1=tanh, Tpp=T0=1, pack T1.
#define INIT2(DST, R0)                                                    \
  {                                                                       \
    _Pragma("unroll") for (int fm = (R0); fm < (R0) + 2; ++fm)            \
        _Pragma("unroll") for (int j = 0; j < 8; ++j) {                   \
      const float xval = ((const float*)&xv[fm][j >> 2])[j & 3];          \
      const float th = fast_tanh(xval);                                   \
      t2[fm][j] = th + th;                                                \
      Tp[fm][j] = th;                                                     \
      Tpp[fm][j] = 1.0f;                                                  \
      DST[fm][j] = (short)f2bf(th);                                       \
    }                                                                     \
  }

// steps q=0..2: afC (packed last step) -> MFMA0; GEN_A under it; MFMA1;
// GEN_B packs afN for next step.
#define STEP_Q012(S, Q, AFC, AFN)                                         \
  {                                                                       \
    ISSUE_B(((S) < 63) ? (S) + 1 : 63, ((Q)&1) ^ 1);                      \
    asm volatile("s_waitcnt vmcnt(4)" ::: "memory");                      \
    __builtin_amdgcn_s_barrier();                                         \
    const unsigned char* Bcur = &Bs[(Q)&1][0];                            \
    MFMA_SLICE(AFC, o0);                                                  \
    GEN_A(af1);                                                           \
    MFMA_SLICE(af1, o1);                                                  \
    GEN_B(AFN);                                                           \
    __builtin_amdgcn_s_barrier();                                         \
  }

// q=3: x(next tile) loads at step start (FIFO: B(s),x8,B(s+1) ->
// vmcnt(12) retires B(s); INIT auto-waits retire x at vmcnt(8)/(4),
// never draining B(s+1)). INIT replaces GEN_B.
#define STEP_Q3(S, ITN, AFC, AFN)                                         \
  {                                                                       \
    LOAD_X2(ITN, 0);                                                      \
    LOAD_X2(ITN, 2);                                                      \
    __builtin_amdgcn_sched_barrier(0);                                    \
    ISSUE_B(((S) < 63) ? (S) + 1 : 63, 0);                                \
    asm volatile("s_waitcnt vmcnt(12)" ::: "memory");                     \
    __builtin_amdgcn_s_barrier();                                         \
    const unsigned char* Bcur = &Bs[1][0];                                \
    MFMA_SLICE(AFC, o0);                                                  \
    GEN_A(af1);                                                           \
    INIT2(AFN, 0);                                                        \
    MFMA_SLICE(af1, o1);                                                  \
    INIT2(AFN, 2);                                                        \
    __builtin_amdgcn_s_barrier();                                         \
  }

__global__ __launch_bounds__(256, 2) void cheby_gemm(
    const float* __restrict__ x, const unsigned char* __restrict__ bws,
    const float* __restrict__ colsum, float* __restrict__ out) {
  const int bid = blockIdx.x;
  const int m0 = (bid >> 2) * BM;
  const int nblk = bid & 3;
  const int n0 = nblk * BN;
  const int tid = threadIdx.x;
  const int lane = tid & 63;
  const int wid = tid >> 6;          // 0..3
  const int wm = (wid >> 1) * 64;
  const int wn = (wid & 1) * 64;
  const int l15 = lane & 15;
  const int lhi = lane >> 4;

  __shared__ __align__(16) unsigned char Bs[2][BN * 128];  // 2 x 16KB

  // per-lane A ownership: rows m0+wm+fm*16+l15 (fm=0..3), i = it*32+lhi*8+j
  const float* xrow[4];
#pragma unroll
  for (int fm = 0; fm < 4; ++fm)
    xrow[fm] = x + (size_t)(m0 + wm + fm * 16 + l15) * IN_DIM + lhi * 8;

  // B fragment addressing: row = wn + fn*16 + l15; row&7 == l15&7.
  const int browbase = (wn + l15) * 128;
  const int rsw = (l15 & 7) << 4;
  const int o0 = (lhi * 16) ^ rsw;
  const int o1 = (64 + lhi * 16) ^ rsw;

  float t2[4][8], Tp[4][8], Tpp[4][8];
  short8 afA[4], afB[4], af1[4];
  float4 xv[4][2];
  f32x4 acc[4][4];
#pragma unroll
  for (int a = 0; a < 4; ++a)
#pragma unroll
    for (int b = 0; b < 4; ++b) acc[a][b] = (f32x4){0.f, 0.f, 0.f, 0.f};

  const unsigned char* bchunk0 = bws + ((size_t)(nblk * 64) << 14);
  const int goff = wid * 4096 + lane * 16;

  // ---- prologue: x(it0), B(0) in flight, afA = T1
  LOAD_X2(0, 0);
  LOAD_X2(0, 2);
  __builtin_amdgcn_sched_barrier(0);
  ISSUE_B(0, 0);
  INIT2(afA, 0);   // compiler inserts waits for xv before the tanh
  INIT2(afA, 2);

  for (int it = 0; it < 16; ++it) {
    const int s0 = it * 4;
    const int itn = (it < 15) ? it + 1 : 15;
    STEP_Q012(s0 + 0, 0, afA, afB);
    STEP_Q012(s0 + 1, 1, afB, afA);
    STEP_Q012(s0 + 2, 2, afA, afB);
    STEP_Q3(s0 + 3, itn, afB, afA);
  }

  // retire the trailing dummy prefetch before the epilogue stores.
  asm volatile("s_waitcnt vmcnt(0)" ::: "memory");

  // ---- epilogue: add d=0 colsum, store f32
  float csv[4];
#pragma unroll
  for (int fn = 0; fn < 4; ++fn) csv[fn] = colsum[n0 + wn + fn * 16 + l15];
  const int lhi4 = lhi * 4;
#pragma unroll
  for (int fm = 0; fm < 4; ++fm) {
    const int r0 = m0 + wm + fm * 16 + lhi4;
#pragma unroll
    for (int fn = 0; fn < 4; ++fn) {
      const int col = n0 + wn + fn * 16 + l15;
#pragma unroll
      for (int r = 0; r < 4; ++r)
        out[(size_t)(r0 + r) * OUT_DIM + col] = acc[fm][fn][r] + csv[fn];
    }
  }
}

extern "C" void kernel_launch(void* const* d_in, const int* in_sizes, int n_in,
                              void* d_out, int out_size, void* d_ws,
                              size_t ws_size, hipStream_t stream) {
  const float* x = (const float*)d_in[0];           // [16384, 512] f32
  const float* coeffs = (const float*)d_in[1];      // [512, 512, 9] f32
  float* out = (float*)d_out;                       // [16384, 512] f32
  unsigned char* bws = (unsigned char*)d_ws;        // 4MB bf16 B tiles
  float* cs = (float*)((unsigned char*)d_ws + ((size_t)4 << 20));  // +2KB

  hipLaunchKernelGGL(cheby_reorder_b, dim3(1024), dim3(256), 0, stream, coeffs,
                     bws);
  hipLaunchKernelGGL(cheby_colsum, dim3(512), dim3(64), 0, stream, coeffs, cs);
  hipLaunchKernelGGL(cheby_gemm, dim3(512), dim3(256), 0, stream, x, bws, cs,
                     out);
}